// Round 2
// baseline (1353.316 us; speedup 1.0000x reference)
//
#include <hip/hip_runtime.h>
#include <math.h>

#define TT 512
#define BB 4096
#define IN_DIM 12
#define HH 32
#define LL 10
#define CC 4
#define NTH 256          // 4 waves: layer groups {0,1},{2,3,4},{5,6,7},{8,9}

typedef _Float16 half8 __attribute__((ext_vector_type(8)));
typedef _Float16 half4 __attribute__((ext_vector_type(4)));
typedef float f32x4 __attribute__((ext_vector_type(4)));

#define LOG2E 1.44269504088896340736f

// Same panel arena as the 10-wave version (f16 units):
#define H_HI 0
#define H_LO (LL * 4 * 512)             // 20480
#define X_HI (H_LO + LL * 2 * 512)      // 30720
#define LDS16_TOT (X_HI + 2 * 512)      // 31744
#define WLO_TOT (LL * 6 * 512)          // 30720  (Wlo frags moved to LDS to save VGPR)

#define MFMA_(A, B, C) C = __builtin_amdgcn_mfma_f32_16x16x32_f16(A, B, C, 0, 0, 0)

template<int N> struct IC { static constexpr int value = N; };

// Round 2: 10-waves/1-layer-each -> 4-waves/2-3-layers-each.
// Evidence: VALUBusy(50%) includes MFMA; pure-VALU ~26% + MFMA ~24% => SIMDs
// ~50% issue-idle. The self-timed 10-wave pipeline's period = one wave's
// iteration LATENCY (LDS round trips + MFMA/trans chains + 9 flag edges'
// acquire/release drains), with {3,3,2,2} SIMD convoying on top.
// Here each wave runs 2-3 INDEPENDENT cells per round (per-layer timestep
// skew sigma), so their latencies overlap inside one instruction stream;
// 6 of 9 layer edges become same-wave program order (no flags, no drains).
// Math identical (hi/lo f16 compensation kept; batched-rcp epilogue kept).
__global__ __launch_bounds__(NTH, 1)
void gru_fused_mfma(const float* __restrict__ x,      // [T][B][12]
                    const float* __restrict__ Wih0,   // [96][12]
                    const float* __restrict__ Whh0,   // [96][32]
                    const float* __restrict__ bih0,   // [96]
                    const float* __restrict__ bhh0,   // [96]
                    const float* __restrict__ Wih,    // [9][96][32]
                    const float* __restrict__ Whh,    // [9][96][32]
                    const float* __restrict__ bih,    // [9][96]
                    const float* __restrict__ bhh,    // [9][96]
                    const int*   __restrict__ lengths,
                    float*       __restrict__ last)   // [B][32]
{
    __shared__ __align__(16) _Float16 lds16[LDS16_TOT];
    __shared__ __align__(16) _Float16 wlo16[WLO_TOT];
    __shared__ int flagE[3];    // inter-wave edges w<->w+1: producer round
    __shared__ int rflagE[3];   // consumer round

    const int tid  = threadIdx.x;
    const int w    = tid >> 6;
    const int lane = tid & 63;
    const int bi16 = lane & 15;
    const int quad = lane >> 4;
    const int bg   = blockIdx.x;

    // layer groups per wave (select chains, not runtime-indexed arrays)
    const int myStart = (w == 0) ? 0 : (w == 1) ? 2 : (w == 2) ? 5 : 8;
    const int myCnt   = (w == 0 || w == 3) ? 2 : 3;

    // ---- zero the panel arena (h0 = 0, zero-padding) ----
    {
        float4 z4 = make_float4(0.f, 0.f, 0.f, 0.f);
        float4* p = (float4*)lds16;
        for (int i = tid; i < LDS16_TOT / 8; i += NTH) p[i] = z4;
    }
    if (tid < 3) { flagE[tid] = -1; rflagE[tid] = -1; }

    const int frow[12] = {0, 0, 16, 16, 32, 32, 48, 48, 64, 80, 64, 80};
    const int fchk[12] = {0, 1, 0, 1, 0, 1, 0, 1, 0, 0, 1, 1};
    const int laneoff = lane * 8;

    // per-owned-layer state (S indexed only by constexpr/unrolled indices)
    int sigS[3], inB[3], inM[3], hiB[3], loB[3], wloB[3];
    half8 Whi[3][12];
    f32x4 biasreg[3][8];
    float hprev[3][8];

#pragma unroll
    for (int s = 0; s < 3; s++) {
        int l = myStart + s; if (l > LL - 1) l = LL - 1;   // clamp; unused if s>=myCnt
        // skew: +1 per layer, +1 extra at each inter-wave boundary (after l1,l4,l7)
        sigS[s] = l + (l >= 2) + (l >= 5) + (l >= 8);
        inB[s]  = (l == 0) ? X_HI : (H_HI + (l - 1) * 2048);
        inM[s]  = (l == 0) ? 1 : 3;
        hiB[s]  = H_HI + l * 2048;
        loB[s]  = H_LO + l * 1024;
        wloB[s] = l * 3072;
#pragma unroll
        for (int i = 0; i < 8; i++) hprev[s][i] = 0.0f;

        if (s < myCnt) {
            const float *Wi, *Wh, *bivec, *bhvec; int wistride;
            if (l == 0) { Wi = Wih0; Wh = Whh0; bivec = bih0; bhvec = bhh0; wistride = IN_DIM; }
            else {
                Wi = Wih + (size_t)(l - 1) * 96 * HH;
                Wh = Whh + (size_t)(l - 1) * 96 * HH;
                bivec = bih + (size_t)(l - 1) * 96;
                bhvec = bhh + (size_t)(l - 1) * 96;
                wistride = HH;
            }
#pragma unroll
            for (int f = 0; f < 12; f++) {
                const float sc = (f < 8) ? -LOG2E : 2.0f * LOG2E;
                int row = frow[f] + bi16;
                const float* src; int kin;
                if (fchk[f] == 0) { src = Wi + (size_t)row * wistride; kin = wistride; }
                else              { src = Wh + (size_t)row * HH;       kin = HH; }
                half8 lo8;
#pragma unroll
                for (int kk = 0; kk < 8; kk++) {
                    int k = quad * 8 + kk;
                    float v = (k < kin) ? src[k] * sc : 0.0f;
                    _Float16 hc = (_Float16)v;
                    Whi[s][f][kk] = hc;
                    lo8[kk] = (_Float16)(v - (float)hc);
                }
                if (fchk[f] == 1) {   // Wlo only for Wh-side frags -> LDS
                    int wloidx = (f < 8) ? (f >> 1) : (f - 6);
                    *(half8*)(wlo16 + wloB[s] + (wloidx << 9) + laneoff) = lo8;
                }
            }
#pragma unroll
            for (int ct = 0; ct < 8; ct++) {
                int g = ct >> 1, jt = ct & 1;
#pragma unroll
                for (int rr = 0; rr < 4; rr++) {
                    int j = jt * 16 + quad * 4 + rr;
                    float v;
                    if      (g == 0) v = -(bivec[j]      + bhvec[j])      * LOG2E;
                    else if (g == 1) v = -(bivec[32 + j] + bhvec[32 + j]) * LOG2E;
                    else if (g == 2) v = bivec[64 + j] * (2.0f * LOG2E);
                    else             v = bhvec[64 + j] * (2.0f * LOG2E);
                    biasreg[s][ct][rr] = v;
                }
            }
        }
    }

    int capT = -1;   // last-layer capture timestep (wave 3, layer 9)
    if (w == 3) {
        int len = lengths[bg * 16 + bi16];
        capT = ((len < 1) ? 1 : len) - 1;
    }

    const int wibase = (quad >> 1) * 128 + bi16 * 8 + (quad & 1) * 4;

    // x staging constants (wave 0, lanes 0-47)
    const int xbb = lane / 3, xkg = lane - xbb * 3;
    const int xq   = (xkg == 2) ? 1 : 0;
    const int xoff = (xkg == 1) ? 4 : 0;
    const int xidx = xq * 128 + xbb * 8 + xoff;
    const bool xlane = (w == 0) && (lane < 48);

    auto stage_x = [&](const float4& xl, int t) {
        half4 h4;
        h4[0] = (_Float16)xl.x; h4[1] = (_Float16)xl.y;
        h4[2] = (_Float16)xl.z; h4[3] = (_Float16)xl.w;
        *(half4*)(lds16 + X_HI + ((t & 1) << 9) + xidx) = h4;
    };

    __syncthreads();   // arena zero + flags visible

    if (xlane) {       // x[0], x[1]; only wave 0 consumes -> no extra sync
        float4 x0 = *(const float4*)(x + (size_t)bg * 192 + lane * 4);
        float4 x1 = *(const float4*)(x + (size_t)BB * IN_DIM + (size_t)bg * 192 + lane * 4);
        stage_x(x0, 0);
        stage_x(x1, 1);
    }

    // one GRU cell for owned slot S at timestep t
    auto cellF = [&](auto Sc, int t) {
        constexpr int S = decltype(Sc)::value;
        const bool lastQ = (w == 3) && (S == 1);   // layer 9
        half8 bxh  = *(const half8*)(lds16 + inB[S] + ((t & inM[S]) << 9) + laneoff);
        half8 bhh2 = *(const half8*)(lds16 + hiB[S] + (((t + 3) & 3) << 9) + laneoff);
        half8 bhl2 = *(const half8*)(lds16 + loB[S] + (((t + 1) & 1) << 9) + laneoff);
        half8 wl[6];
#pragma unroll
        for (int j = 0; j < 6; j++)
            wl[j] = *(const half8*)(wlo16 + wloB[S] + (j << 9) + laneoff);

        f32x4 acc[8];
#pragma unroll
        for (int ct = 0; ct < 4; ct++) {
            acc[ct] = __builtin_amdgcn_mfma_f32_16x16x32_f16(
                          Whi[S][ct * 2 + 0], bxh, biasreg[S][ct], 0, 0, 0);
            MFMA_(Whi[S][ct * 2 + 1], bhh2, acc[ct]);
            MFMA_(Whi[S][ct * 2 + 1], bhl2, acc[ct]);
            MFMA_(wl[ct],             bhh2, acc[ct]);
        }
#pragma unroll
        for (int jt = 0; jt < 2; jt++) {
            acc[4 + jt] = __builtin_amdgcn_mfma_f32_16x16x32_f16(
                              Whi[S][8 + jt], bxh, biasreg[S][4 + jt], 0, 0, 0);
            acc[6 + jt] = __builtin_amdgcn_mfma_f32_16x16x32_f16(
                              Whi[S][10 + jt], bhh2, biasreg[S][6 + jt], 0, 0, 0);
            MFMA_(Whi[S][10 + jt], bhl2, acc[6 + jt]);
            MFMA_(wl[4 + jt],      bhh2, acc[6 + jt]);
        }

        // batched-rcp epilogue (R1): 8 rcp/cell
#pragma unroll
        for (int jt = 0; jt < 2; jt++) {
            f32x4 R = acc[0 + jt], Z = acc[2 + jt];
            f32x4 IN_ = acc[4 + jt], HN = acc[6 + jt];
            half4 h4, l4;
            float hv[4];
#pragma unroll
            for (int pr = 0; pr < 2; pr++) {
                const int r0 = pr * 2, r1 = pr * 2 + 1;
                float a0 = 1.0f + __builtin_amdgcn_exp2f(R[r0]);
                float b0 = 1.0f + __builtin_amdgcn_exp2f(Z[r0]);
                float a1 = 1.0f + __builtin_amdgcn_exp2f(R[r1]);
                float b1 = 1.0f + __builtin_amdgcn_exp2f(Z[r1]);
                float p0 = a0 * b0, p1 = a1 * b1;
                float q  = __builtin_amdgcn_rcpf(p0 * p1);
                float q0 = q * p1, q1 = q * p0;
                float rv0 = q0 * b0, zv0 = q0 * a0;
                float rv1 = q1 * b1, zv1 = q1 * a1;
                float ea0 = __builtin_amdgcn_exp2f(fmaf(rv0, HN[r0], IN_[r0]));
                float ea1 = __builtin_amdgcn_exp2f(fmaf(rv1, HN[r1], IN_[r1]));
                float d0 = ea0 + 1.0f, d1 = ea1 + 1.0f;
                float qn = __builtin_amdgcn_rcpf(d0 * d1);
                float nv0 = fmaf(-2.0f, qn * d1, 1.0f);
                float nv1 = fmaf(-2.0f, qn * d0, 1.0f);
                float h0 = fmaf(zv0, hprev[S][jt * 4 + r0] - nv0, nv0);
                float h1 = fmaf(zv1, hprev[S][jt * 4 + r1] - nv1, nv1);
                hprev[S][jt * 4 + r0] = h0;
                hprev[S][jt * 4 + r1] = h1;
                _Float16 hh0 = (_Float16)h0, hh1 = (_Float16)h1;
                h4[r0] = hh0; h4[r1] = hh1;
                l4[r0] = (_Float16)(h0 - (float)hh0);
                l4[r1] = (_Float16)(h1 - (float)hh1);
                hv[r0] = h0; hv[r1] = h1;
            }
            int wi = jt * 256 + wibase;
            *(half4*)(lds16 + hiB[S] + ((t & 3) << 9) + wi) = h4;
            *(half4*)(lds16 + loB[S] + ((t & 1) << 9) + wi) = l4;
            if (lastQ && t == capT) {
                float4 o = make_float4(hv[0], hv[1], hv[2], hv[3]);
                *(float4*)(last + (size_t)(bg * 16 + bi16) * HH + jt * 16 + quad * 4) = o;
            }
        }
    };

#define RUNCELL(S, rr)                                                    \
    do { if ((S) < myCnt) { const int t_ = (rr) - sigS[(S)];              \
         if (t_ >= 0 && t_ < TT) cellF(IC<(S)>{}, t_); } } while (0)

    // rounds: layer l computes t = rnd - sigma_l; last: t9 = rnd-12 -> 524 rounds
    for (int rnd = 0; rnd < TT + 12; rnd += 2) {
        // inter-wave edges only (3 of them); round-number protocol:
        // both sides need the partner's round rnd-1 complete before this pair
        if (w > 0) {
            while (__hip_atomic_load(&flagE[w - 1], __ATOMIC_ACQUIRE,
                                     __HIP_MEMORY_SCOPE_WORKGROUP) < rnd - 1)
                __builtin_amdgcn_s_sleep(1);
        }
        if (w < 3) {
            while (__hip_atomic_load(&rflagE[w], __ATOMIC_ACQUIRE,
                                     __HIP_MEMORY_SCOPE_WORKGROUP) < rnd - 1)
                __builtin_amdgcn_s_sleep(1);
        }

        // wave 0: issue global x loads early (t = rnd+2, rnd+3)
        float4 xa0, xa1;
        bool dl0 = false, dl1 = false;
        if (xlane) {
            if (rnd + 2 < TT) {
                xa0 = *(const float4*)(x + (size_t)(rnd + 2) * BB * IN_DIM +
                                       (size_t)bg * 192 + lane * 4);
                dl0 = true;
            }
            if (rnd + 3 < TT) {
                xa1 = *(const float4*)(x + (size_t)(rnd + 3) * BB * IN_DIM +
                                       (size_t)bg * 192 + lane * 4);
                dl1 = true;
            }
        }

        RUNCELL(0, rnd);     RUNCELL(1, rnd);     RUNCELL(2, rnd);
        RUNCELL(0, rnd + 1); RUNCELL(1, rnd + 1); RUNCELL(2, rnd + 1);

        if (dl0) stage_x(xa0, rnd + 2);   // slot rnd&1 already read this pair
        if (dl1) stage_x(xa1, rnd + 3);

        if (lane == 0) {   // release: drains this wave's DS ops first
            if (w < 3)
                __hip_atomic_store(&flagE[w], rnd + 1, __ATOMIC_RELEASE,
                                   __HIP_MEMORY_SCOPE_WORKGROUP);
            if (w > 0)
                __hip_atomic_store(&rflagE[w - 1], rnd + 1, __ATOMIC_RELEASE,
                                   __HIP_MEMORY_SCOPE_WORKGROUP);
        }
    }
#undef RUNCELL
}

__global__ __launch_bounds__(256)
void fc_head(const float* __restrict__ last,
             const float* __restrict__ fcW,   // [C][H]
             const float* __restrict__ fcb,   // [C]
             float* __restrict__ out)         // [B][C]
{
    int b = blockIdx.x * blockDim.x + threadIdx.x;
    if (b >= BB) return;
    float lg[CC];
#pragma unroll
    for (int c = 0; c < CC; c++) lg[c] = fcb[c];
#pragma unroll
    for (int j = 0; j < HH; j++) {
        float h = last[(size_t)b * HH + j];
#pragma unroll
        for (int c = 0; c < CC; c++) lg[c] = fmaf(fcW[c * HH + j], h, lg[c]);
    }
    float m = lg[0];
#pragma unroll
    for (int c = 1; c < CC; c++) m = fmaxf(m, lg[c]);
    float s = 0.0f;
#pragma unroll
    for (int c = 0; c < CC; c++) s += __expf(lg[c] - m);
    float lse = m + logf(s);
#pragma unroll
    for (int c = 0; c < CC; c++) out[(size_t)b * CC + c] = lg[c] - lse;
}

extern "C" void kernel_launch(void* const* d_in, const int* in_sizes, int n_in,
                              void* d_out, int out_size, void* d_ws, size_t ws_size,
                              hipStream_t stream)
{
    const float* x    = (const float*)d_in[0];
    const float* Wih0 = (const float*)d_in[1];
    const float* Whh0 = (const float*)d_in[2];
    const float* bih0 = (const float*)d_in[3];
    const float* bhh0 = (const float*)d_in[4];
    const float* Wih  = (const float*)d_in[5];
    const float* Whh  = (const float*)d_in[6];
    const float* bih  = (const float*)d_in[7];
    const float* bhh  = (const float*)d_in[8];
    const float* fcW  = (const float*)d_in[9];
    const float* fcb  = (const float*)d_in[10];
    const int*   lens = (const int*)d_in[11];
    float* out = (float*)d_out;

    float* last = (float*)d_ws;   // [B][32] = 512 KB

    gru_fused_mfma<<<dim3(BB / 16), dim3(NTH), 0, stream>>>(
        x, Wih0, Whh0, bih0, bhh0, Wih, Whh, bih, bhh, lens, last);

    fc_head<<<dim3(BB / 256), dim3(256), 0, stream>>>(last, fcW, fcb, out);
}

// Round 4
// 1010.673 us; speedup vs baseline: 1.3390x; 1.3390x over previous
//
#include <hip/hip_runtime.h>
#include <math.h>

#define TT 512
#define BB 4096
#define IN_DIM 12
#define HH 32
#define LL 10
#define CC 4
#define NTH (LL * 64)        // 640 threads = 10 waves, one per layer

typedef _Float16 half8 __attribute__((ext_vector_type(8)));
typedef _Float16 half4 __attribute__((ext_vector_type(4)));
typedef float f32x4 __attribute__((ext_vector_type(4)));
typedef float f32x2 __attribute__((ext_vector_type(2)));

#define LOG2E 1.44269504088896340736f

// f16-unit offsets in the LDS arena (total 53248 f16 = 104 KB static):
//  H_HI: per-layer h hi panels, 8 slots (mod-8 of t) — cross-wave handoff.
//        8 slots (was 4): backward-edge slack t-3 -> t-7, decouples
//        producer/consumer jitter (LDS is free at 1 block/CU).
//  H_LO: per-layer h lo panels, 2 slots — wave-internal (own recurrence only)
//  X_HI: wave-0 x panels, 4 slots — wave-internal
#define H_HI 0
#define H_LO (LL * 8 * 512)             // 40960
#define X_HI (H_LO + LL * 2 * 512)      // 51200
#define LDS16_TOT (X_HI + 4 * 512)      // 53248

#define MFMA_(A, B, C) C = __builtin_amdgcn_mfma_f32_16x16x32_f16(A, B, C, 0, 0, 0)

// Fused 10-layer GRU: temporal pipeline across 10 waves, MFMA cells,
// SELF-TIMED producer-consumer sync (no __syncthreads in the main loop).
//
// R2 lesson: 4-wave/multi-cell restructure needs ~370 VGPR (got 196) ->
// compiler serialized cells; 2.5 waves/SIMD of TLP is load-bearing. Revert.
// R3/R4 (this round), on the proven 10-wave base:
//  (a) epilogue packed as f32x2 over row-pairs (adjacent acc subregisters,
//      no marshaling movs) -> v_pk_{add,mul,fma}_f32, ~halves pure-VALU
//      epilogue issue. Operation order identical to R1 -> bit-same results.
//      (R3's shufflevector needed syntactic constants; use element access.)
//  (b) s_setprio(1) around the MFMA cluster (waves are phase-diverse).
//  (c) H_HI 8 slots: bwd back-pressure threshold t-3 -> t-7.
__global__ __launch_bounds__(NTH, 2)
void gru_fused_mfma(const float* __restrict__ x,      // [T][B][12]
                    const float* __restrict__ Wih0,   // [96][12]
                    const float* __restrict__ Whh0,   // [96][32]
                    const float* __restrict__ bih0,   // [96]
                    const float* __restrict__ bhh0,   // [96]
                    const float* __restrict__ Wih,    // [9][96][32]
                    const float* __restrict__ Whh,    // [9][96][32]
                    const float* __restrict__ bih,    // [9][96]
                    const float* __restrict__ bhh,    // [9][96]
                    const int*   __restrict__ lengths,
                    float*       __restrict__ last)   // [B][32]
{
    __shared__ __align__(16) _Float16 lds16[LDS16_TOT];
    __shared__ int flagS[LL];    // producer progress
    __shared__ int rflagS[LL];   // consumer progress (indexed by producer)

    const int tid  = threadIdx.x;
    const int w    = tid >> 6;      // layer
    const int lane = tid & 63;
    const int bi16 = lane & 15;     // batch col within group
    const int quad = lane >> 4;
    const int bg   = blockIdx.x;    // batch group (16 elems)

    // ---- zero the arena (h0 = 0, zero-padding) + init flags ----
    {
        float4 z4 = make_float4(0.f, 0.f, 0.f, 0.f);
        float4* p = (float4*)lds16;
        for (int i = tid; i < LDS16_TOT / 8; i += NTH) p[i] = z4;
    }
    if (lane == 0) { flagS[w] = -1; rflagS[w] = -1; }
    __syncthreads();

    // ---- per-wave weight pointers ----
    const float *Wi, *Wh, *bivec, *bhvec;
    int wistride;
    if (w == 0) { Wi = Wih0; Wh = Whh0; bivec = bih0; bhvec = bhh0; wistride = IN_DIM; }
    else {
        Wi = Wih + (size_t)(w - 1) * 96 * HH;
        Wh = Whh + (size_t)(w - 1) * 96 * HH;
        bivec = bih + (size_t)(w - 1) * 96;
        bhvec = bhh + (size_t)(w - 1) * 96;
        wistride = HH;
    }

    // ---- stationary A-fragments (pre-scaled) ----
    // f0..f7: r/z tiles, pairs (chunk0=Wi, chunk1=Wh); f8,f9: IN (Wi);
    // f10,f11: HN (Wh). Wlo kept only for the 6 h-side (Wh) frags.
    const int frow[12] = {0, 0, 16, 16, 32, 32, 48, 48, 64, 80, 64, 80};
    const int fchk[12] = {0, 1, 0, 1, 0, 1, 0, 1, 0, 0, 1, 1};
    half8 Whi[12], Wlo[6];
#pragma unroll
    for (int f = 0; f < 12; f++) {
        const float sc = (f < 8) ? -LOG2E : 2.0f * LOG2E;
        int row = frow[f] + bi16;
        const float* src; int kin;
        if (fchk[f] == 0) { src = Wi + (size_t)row * wistride; kin = wistride; }
        else              { src = Wh + (size_t)row * HH;       kin = HH; }
        int wloidx = (f < 8) ? (f >> 1) : (f - 6);
#pragma unroll
        for (int kk = 0; kk < 8; kk++) {
            int k = quad * 8 + kk;
            float v = (k < kin) ? src[k] * sc : 0.0f;
            _Float16 h = (_Float16)v;
            Whi[f][kk] = h;
            if (fchk[f] == 1) Wlo[wloidx][kk] = (_Float16)(v - (float)h);
        }
    }

    // ---- biases in registers (pre-scaled, per C-tile f32x4) ----
    f32x4 biasreg[8];
#pragma unroll
    for (int ct = 0; ct < 8; ct++) {
        int g = ct >> 1, jt = ct & 1;
#pragma unroll
        for (int r = 0; r < 4; r++) {
            int j = jt * 16 + quad * 4 + r;
            float v;
            if      (g == 0) v = -(bivec[j]      + bhvec[j])      * LOG2E;
            else if (g == 1) v = -(bivec[32 + j] + bhvec[32 + j]) * LOG2E;
            else if (g == 2) v = bivec[64 + j] * (2.0f * LOG2E);
            else             v = bhvec[64 + j] * (2.0f * LOG2E);
            biasreg[ct][r] = v;
        }
    }

    int capT = -1;   // last-layer capture timestep per lane
    if (w == LL - 1) {
        int len = lengths[bg * 16 + bi16];
        capT = ((len < 1) ? 1 : len) - 1;
    }

    const int laneoff = lane * 8;
    const int inbase  = (w == 0) ? X_HI : (H_HI + (w - 1) * 4096);
    const int inmask  = (w == 0) ? 3 : 7;
    const int ownhi   = H_HI + w * 4096;
    const int ownlo   = H_LO + w * 1024;
    const int wibase  = (quad >> 1) * 128 + bi16 * 8 + (quad & 1) * 4;

    // x staging constants (wave 0, lanes 0-47)
    const int xbb = lane / 3, xkg = lane - xbb * 3;
    const int xq   = (xkg == 2) ? 1 : 0;
    const int xoff = (xkg == 1) ? 4 : 0;
    const int xidx = xq * 128 + xbb * 8 + xoff;
    const bool xlane = (w == 0) && (lane < 48);

    auto stage_x = [&](const float4& xl, int t) {
        half4 h4;
        h4[0] = (_Float16)xl.x; h4[1] = (_Float16)xl.y;
        h4[2] = (_Float16)xl.z; h4[3] = (_Float16)xl.w;
        *(half4*)(lds16 + X_HI + ((t & 3) << 9) + xidx) = h4;
    };

    // stage x[0], x[1]
    if (xlane) {
        float4 x0 = *(const float4*)(x + (size_t)bg * 192 + lane * 4);
        float4 x1 = *(const float4*)(x + (size_t)BB * IN_DIM + (size_t)bg * 192 + lane * 4);
        stage_x(x0, 0);
        stage_x(x1, 1);
    }

    f32x2 hprev[4];   // hprev[jt*2+pr] = rows (2pr, 2pr+1) of jt-half
#pragma unroll
    for (int i = 0; i < 4; i++) { hprev[i][0] = 0.0f; hprev[i][1] = 0.0f; }

    __syncthreads();   // flags + h0 + x0/x1 visible before self-timed phase

    auto substep = [&](int t) {
        // B-fragments: input (f16 hi only) + own h (hi+lo)
        half8 bxh = *(const half8*)(lds16 + inbase + ((t & inmask) << 9) + laneoff);
        half8 bhh = *(const half8*)(lds16 + ownhi + (((t + 7) & 7) << 9) + laneoff);
        half8 bhl = *(const half8*)(lds16 + ownlo + (((t + 1) & 1) << 9) + laneoff);

        f32x4 acc[8];

        // 24 MFMAs: r/z tiles 4 each; IN 1 each; HN 3 each.
        // First MFMA of each tile takes biasreg as the C operand directly.
        __builtin_amdgcn_s_setprio(1);
#pragma unroll
        for (int ct = 0; ct < 4; ct++) {
            acc[ct] = __builtin_amdgcn_mfma_f32_16x16x32_f16(
                          Whi[ct * 2 + 0], bxh, biasreg[ct], 0, 0, 0);
            MFMA_(Whi[ct * 2 + 1], bhh, acc[ct]);
            MFMA_(Whi[ct * 2 + 1], bhl, acc[ct]);
            MFMA_(Wlo[ct],         bhh, acc[ct]);
        }
#pragma unroll
        for (int jt = 0; jt < 2; jt++) {
            acc[4 + jt] = __builtin_amdgcn_mfma_f32_16x16x32_f16(
                              Whi[8 + jt], bxh, biasreg[4 + jt], 0, 0, 0);
            acc[6 + jt] = __builtin_amdgcn_mfma_f32_16x16x32_f16(
                              Whi[10 + jt], bhh, biasreg[6 + jt], 0, 0, 0);
            MFMA_(Whi[10 + jt], bhl, acc[6 + jt]);
            MFMA_(Wlo[4 + jt],  bhh, acc[6 + jt]);
        }
        __builtin_amdgcn_s_setprio(0);

        // Epilogue, f32x2-packed over row pairs (adjacent acc subregisters ->
        // v_pk_* ops, no marshaling). Same op order as the scalar version:
        // batched rcp (1 per 4 sigmoid denoms, 1 per 2 tanh denoms).
#pragma unroll
        for (int jt = 0; jt < 2; jt++) {
            half4 h4, l4;
            float hv[4];
#pragma unroll
            for (int pr = 0; pr < 2; pr++) {
                f32x2 R2, Z2, I2, H2;
                R2[0] = acc[0 + jt][2 * pr]; R2[1] = acc[0 + jt][2 * pr + 1];
                Z2[0] = acc[2 + jt][2 * pr]; Z2[1] = acc[2 + jt][2 * pr + 1];
                I2[0] = acc[4 + jt][2 * pr]; I2[1] = acc[4 + jt][2 * pr + 1];
                H2[0] = acc[6 + jt][2 * pr]; H2[1] = acc[6 + jt][2 * pr + 1];
                f32x2 av, bv;
                av[0] = __builtin_amdgcn_exp2f(R2[0]);
                av[1] = __builtin_amdgcn_exp2f(R2[1]);
                bv[0] = __builtin_amdgcn_exp2f(Z2[0]);
                bv[1] = __builtin_amdgcn_exp2f(Z2[1]);
                av = av + 1.0f;                       // pk_add
                bv = bv + 1.0f;
                f32x2 pv = av * bv;                   // pk_mul
                float q  = __builtin_amdgcn_rcpf(pv[0] * pv[1]);
                f32x2 qs; qs[0] = q * pv[1]; qs[1] = q * pv[0];   // = 1/p0, 1/p1
                f32x2 rv = qs * bv;                   // = 1/a
                f32x2 zv = qs * av;                   // = 1/b
                f32x2 na = __builtin_elementwise_fma(rv, H2, I2);
                f32x2 ea;
                ea[0] = __builtin_amdgcn_exp2f(na[0]);
                ea[1] = __builtin_amdgcn_exp2f(na[1]);
                f32x2 dv = ea + 1.0f;
                float qn = __builtin_amdgcn_rcpf(dv[0] * dv[1]);
                f32x2 qv; qv[0] = qn * dv[1]; qv[1] = qn * dv[0]; // = 1/d0, 1/d1
                f32x2 m2; m2[0] = -2.0f; m2[1] = -2.0f;
                f32x2 o1; o1[0] = 1.0f;  o1[1] = 1.0f;
                f32x2 nv = __builtin_elementwise_fma(m2, qv, o1);
                f32x2 hp = hprev[jt * 2 + pr];
                f32x2 hn = __builtin_elementwise_fma(zv, hp - nv, nv);
                hprev[jt * 2 + pr] = hn;
                _Float16 hh0 = (_Float16)hn[0], hh1 = (_Float16)hn[1];
                f32x2 hi32; hi32[0] = (float)hh0; hi32[1] = (float)hh1;
                f32x2 lo2 = hn - hi32;               // pk_sub
                h4[2 * pr]     = hh0; h4[2 * pr + 1] = hh1;
                l4[2 * pr]     = (_Float16)lo2[0];
                l4[2 * pr + 1] = (_Float16)lo2[1];
                hv[2 * pr]     = hn[0];
                hv[2 * pr + 1] = hn[1];
            }
            int wi = jt * 256 + wibase;
            *(half4*)(lds16 + ownhi + ((t & 7) << 9) + wi) = h4;
            *(half4*)(lds16 + ownlo + ((t & 1) << 9) + wi) = l4;
            if (w == LL - 1 && t == capT) {
                float4 o = make_float4(hv[0], hv[1], hv[2], hv[3]);
                *(float4*)(last + (size_t)(bg * 16 + bi16) * HH + jt * 16 + quad * 4) = o;
            }
        }
    };

    for (int t = 0; t < TT; t += 2) {
        // fwd sync: input panels for t, t+1 published by wave w-1
        if (w > 0) {
            while (__hip_atomic_load(&flagS[w - 1], __ATOMIC_ACQUIRE,
                                     __HIP_MEMORY_SCOPE_WORKGROUP) < t + 1)
                __builtin_amdgcn_s_sleep(1);
        }
        // bwd sync: writing t+1 reuses slot of t-7 — consumer must be done
        if (w < LL - 1) {
            while (__hip_atomic_load(&rflagS[w], __ATOMIC_ACQUIRE,
                                     __HIP_MEMORY_SCOPE_WORKGROUP) < t - 7)
                __builtin_amdgcn_s_sleep(1);
        }

        // wave 0: issue global x loads for t+2, t+3 early
        float4 xa0, xa1;
        bool dl0 = false, dl1 = false;
        if (xlane) {
            if (t + 2 < TT) {
                xa0 = *(const float4*)(x + (size_t)(t + 2) * BB * IN_DIM +
                                       (size_t)bg * 192 + lane * 4);
                dl0 = true;
            }
            if (t + 3 < TT) {
                xa1 = *(const float4*)(x + (size_t)(t + 3) * BB * IN_DIM +
                                       (size_t)bg * 192 + lane * 4);
                dl1 = true;
            }
        }

        substep(t);
        substep(t + 1);

        if (dl0) stage_x(xa0, t + 2);   // 4 x-slots: no overlap with t, t+1
        if (dl1) stage_x(xa1, t + 3);

        if (lane == 0) {
            // release: waits for this wave's DS ops (panel writes AND input
            // reads) to drain before publishing
            if (w < LL - 1)
                __hip_atomic_store(&flagS[w], t + 1, __ATOMIC_RELEASE,
                                   __HIP_MEMORY_SCOPE_WORKGROUP);
            if (w > 0)
                __hip_atomic_store(&rflagS[w - 1], t + 1, __ATOMIC_RELEASE,
                                   __HIP_MEMORY_SCOPE_WORKGROUP);
        }
    }
}

__global__ __launch_bounds__(256)
void fc_head(const float* __restrict__ last,
             const float* __restrict__ fcW,   // [C][H]
             const float* __restrict__ fcb,   // [C]
             float* __restrict__ out)         // [B][C]
{
    int b = blockIdx.x * blockDim.x + threadIdx.x;
    if (b >= BB) return;
    float lg[CC];
#pragma unroll
    for (int c = 0; c < CC; c++) lg[c] = fcb[c];
#pragma unroll
    for (int j = 0; j < HH; j++) {
        float h = last[(size_t)b * HH + j];
#pragma unroll
        for (int c = 0; c < CC; c++) lg[c] = fmaf(fcW[c * HH + j], h, lg[c]);
    }
    float m = lg[0];
#pragma unroll
    for (int c = 1; c < CC; c++) m = fmaxf(m, lg[c]);
    float s = 0.0f;
#pragma unroll
    for (int c = 0; c < CC; c++) s += __expf(lg[c] - m);
    float lse = m + logf(s);
#pragma unroll
    for (int c = 0; c < CC; c++) out[(size_t)b * CC + c] = lg[c] - lse;
}

extern "C" void kernel_launch(void* const* d_in, const int* in_sizes, int n_in,
                              void* d_out, int out_size, void* d_ws, size_t ws_size,
                              hipStream_t stream)
{
    const float* x    = (const float*)d_in[0];
    const float* Wih0 = (const float*)d_in[1];
    const float* Whh0 = (const float*)d_in[2];
    const float* bih0 = (const float*)d_in[3];
    const float* bhh0 = (const float*)d_in[4];
    const float* Wih  = (const float*)d_in[5];
    const float* Whh  = (const float*)d_in[6];
    const float* bih  = (const float*)d_in[7];
    const float* bhh  = (const float*)d_in[8];
    const float* fcW  = (const float*)d_in[9];
    const float* fcb  = (const float*)d_in[10];
    const int*   lens = (const int*)d_in[11];
    float* out = (float*)d_out;

    float* last = (float*)d_ws;   // [B][32] = 512 KB

    gru_fused_mfma<<<dim3(BB / 16), dim3(NTH), 0, stream>>>(
        x, Wih0, Whh0, bih0, bhh0, Wih, Whh, bih, bhh, lens, last);

    fc_head<<<dim3(BB / 256), dim3(256), 0, stream>>>(last, fcW, fcb, out);
}

// Round 5
// 908.730 us; speedup vs baseline: 1.4892x; 1.1122x over previous
//
#include <hip/hip_runtime.h>
#include <math.h>

#define TT 512
#define BB 4096
#define IN_DIM 12
#define HH 32
#define LL 10
#define CC 4
#define NTH (LL * 64)        // 640 threads = 10 waves, one per layer

typedef _Float16 half8 __attribute__((ext_vector_type(8)));
typedef _Float16 half4 __attribute__((ext_vector_type(4)));
typedef float f32x4 __attribute__((ext_vector_type(4)));
typedef float f32x2 __attribute__((ext_vector_type(2)));

#define LOG2E 1.44269504088896340736f

// f16-unit offsets in the LDS arena (total 53248 f16 = 104 KB static):
//  H_HI: per-layer h hi panels, 8 slots (mod-8 of t) — cross-wave handoff.
//  H_LO: per-layer h lo panels, 2 slots — wave-internal (own recurrence only)
//  X_HI: wave-0 x panels, 4 slots — wave-internal
#define H_HI 0
#define H_LO (LL * 8 * 512)             // 40960
#define X_HI (H_LO + LL * 2 * 512)      // 51200
#define LDS16_TOT (X_HI + 4 * 512)      // 53248

#define MFMA_(A, B, C) C = __builtin_amdgcn_mfma_f32_16x16x32_f16(A, B, C, 0, 0, 0)

// Fused 10-layer GRU: temporal pipeline across 10 waves, MFMA cells,
// SELF-TIMED producer-consumer sync (no __syncthreads in the main loop).
//
// R2 lesson: 4-wave/multi-cell restructure needs ~370 VGPR (got 196) ->
// compiler serialized cells; 2.5 waves/SIMD of TLP is load-bearing.
// R4 lesson: bundling = attribution debt. R4 = pk-epilogue + setprio +
// 8-slot H_HI regressed to 1010us despite VALUBusy dropping 50->44 as
// predicted. Suspect: s_setprio(1) around MFMA starves co-resident waves'
// EPILOGUE VALU (the recurrence critical path) -> publish delays cascade
// down the layer chain (same mechanism as T5's GEMM regression).
// R5 (this round): R4 minus setprio, nothing else -> single-variable
// attribution; if ~900-925us, pk+8slot confirmed good vs R1's 952.
__global__ __launch_bounds__(NTH, 2)
void gru_fused_mfma(const float* __restrict__ x,      // [T][B][12]
                    const float* __restrict__ Wih0,   // [96][12]
                    const float* __restrict__ Whh0,   // [96][32]
                    const float* __restrict__ bih0,   // [96]
                    const float* __restrict__ bhh0,   // [96]
                    const float* __restrict__ Wih,    // [9][96][32]
                    const float* __restrict__ Whh,    // [9][96][32]
                    const float* __restrict__ bih,    // [9][96]
                    const float* __restrict__ bhh,    // [9][96]
                    const int*   __restrict__ lengths,
                    float*       __restrict__ last)   // [B][32]
{
    __shared__ __align__(16) _Float16 lds16[LDS16_TOT];
    __shared__ int flagS[LL];    // producer progress
    __shared__ int rflagS[LL];   // consumer progress (indexed by producer)

    const int tid  = threadIdx.x;
    const int w    = tid >> 6;      // layer
    const int lane = tid & 63;
    const int bi16 = lane & 15;     // batch col within group
    const int quad = lane >> 4;
    const int bg   = blockIdx.x;    // batch group (16 elems)

    // ---- zero the arena (h0 = 0, zero-padding) + init flags ----
    {
        float4 z4 = make_float4(0.f, 0.f, 0.f, 0.f);
        float4* p = (float4*)lds16;
        for (int i = tid; i < LDS16_TOT / 8; i += NTH) p[i] = z4;
    }
    if (lane == 0) { flagS[w] = -1; rflagS[w] = -1; }
    __syncthreads();

    // ---- per-wave weight pointers ----
    const float *Wi, *Wh, *bivec, *bhvec;
    int wistride;
    if (w == 0) { Wi = Wih0; Wh = Whh0; bivec = bih0; bhvec = bhh0; wistride = IN_DIM; }
    else {
        Wi = Wih + (size_t)(w - 1) * 96 * HH;
        Wh = Whh + (size_t)(w - 1) * 96 * HH;
        bivec = bih + (size_t)(w - 1) * 96;
        bhvec = bhh + (size_t)(w - 1) * 96;
        wistride = HH;
    }

    // ---- stationary A-fragments (pre-scaled) ----
    // f0..f7: r/z tiles, pairs (chunk0=Wi, chunk1=Wh); f8,f9: IN (Wi);
    // f10,f11: HN (Wh). Wlo kept only for the 6 h-side (Wh) frags.
    const int frow[12] = {0, 0, 16, 16, 32, 32, 48, 48, 64, 80, 64, 80};
    const int fchk[12] = {0, 1, 0, 1, 0, 1, 0, 1, 0, 0, 1, 1};
    half8 Whi[12], Wlo[6];
#pragma unroll
    for (int f = 0; f < 12; f++) {
        const float sc = (f < 8) ? -LOG2E : 2.0f * LOG2E;
        int row = frow[f] + bi16;
        const float* src; int kin;
        if (fchk[f] == 0) { src = Wi + (size_t)row * wistride; kin = wistride; }
        else              { src = Wh + (size_t)row * HH;       kin = HH; }
        int wloidx = (f < 8) ? (f >> 1) : (f - 6);
#pragma unroll
        for (int kk = 0; kk < 8; kk++) {
            int k = quad * 8 + kk;
            float v = (k < kin) ? src[k] * sc : 0.0f;
            _Float16 h = (_Float16)v;
            Whi[f][kk] = h;
            if (fchk[f] == 1) Wlo[wloidx][kk] = (_Float16)(v - (float)h);
        }
    }

    // ---- biases in registers (pre-scaled, per C-tile f32x4) ----
    f32x4 biasreg[8];
#pragma unroll
    for (int ct = 0; ct < 8; ct++) {
        int g = ct >> 1, jt = ct & 1;
#pragma unroll
        for (int r = 0; r < 4; r++) {
            int j = jt * 16 + quad * 4 + r;
            float v;
            if      (g == 0) v = -(bivec[j]      + bhvec[j])      * LOG2E;
            else if (g == 1) v = -(bivec[32 + j] + bhvec[32 + j]) * LOG2E;
            else if (g == 2) v = bivec[64 + j] * (2.0f * LOG2E);
            else             v = bhvec[64 + j] * (2.0f * LOG2E);
            biasreg[ct][r] = v;
        }
    }

    int capT = -1;   // last-layer capture timestep per lane
    if (w == LL - 1) {
        int len = lengths[bg * 16 + bi16];
        capT = ((len < 1) ? 1 : len) - 1;
    }

    const int laneoff = lane * 8;
    const int inbase  = (w == 0) ? X_HI : (H_HI + (w - 1) * 4096);
    const int inmask  = (w == 0) ? 3 : 7;
    const int ownhi   = H_HI + w * 4096;
    const int ownlo   = H_LO + w * 1024;
    const int wibase  = (quad >> 1) * 128 + bi16 * 8 + (quad & 1) * 4;

    // x staging constants (wave 0, lanes 0-47)
    const int xbb = lane / 3, xkg = lane - xbb * 3;
    const int xq   = (xkg == 2) ? 1 : 0;
    const int xoff = (xkg == 1) ? 4 : 0;
    const int xidx = xq * 128 + xbb * 8 + xoff;
    const bool xlane = (w == 0) && (lane < 48);

    auto stage_x = [&](const float4& xl, int t) {
        half4 h4;
        h4[0] = (_Float16)xl.x; h4[1] = (_Float16)xl.y;
        h4[2] = (_Float16)xl.z; h4[3] = (_Float16)xl.w;
        *(half4*)(lds16 + X_HI + ((t & 3) << 9) + xidx) = h4;
    };

    // stage x[0], x[1]
    if (xlane) {
        float4 x0 = *(const float4*)(x + (size_t)bg * 192 + lane * 4);
        float4 x1 = *(const float4*)(x + (size_t)BB * IN_DIM + (size_t)bg * 192 + lane * 4);
        stage_x(x0, 0);
        stage_x(x1, 1);
    }

    f32x2 hprev[4];   // hprev[jt*2+pr] = rows (2pr, 2pr+1) of jt-half
#pragma unroll
    for (int i = 0; i < 4; i++) { hprev[i][0] = 0.0f; hprev[i][1] = 0.0f; }

    __syncthreads();   // flags + h0 + x0/x1 visible before self-timed phase

    auto substep = [&](int t) {
        // B-fragments: input (f16 hi only) + own h (hi+lo)
        half8 bxh = *(const half8*)(lds16 + inbase + ((t & inmask) << 9) + laneoff);
        half8 bhh = *(const half8*)(lds16 + ownhi + (((t + 7) & 7) << 9) + laneoff);
        half8 bhl = *(const half8*)(lds16 + ownlo + (((t + 1) & 1) << 9) + laneoff);

        f32x4 acc[8];

        // 24 MFMAs: r/z tiles 4 each; IN 1 each; HN 3 each.
        // First MFMA of each tile takes biasreg as the C operand directly.
#pragma unroll
        for (int ct = 0; ct < 4; ct++) {
            acc[ct] = __builtin_amdgcn_mfma_f32_16x16x32_f16(
                          Whi[ct * 2 + 0], bxh, biasreg[ct], 0, 0, 0);
            MFMA_(Whi[ct * 2 + 1], bhh, acc[ct]);
            MFMA_(Whi[ct * 2 + 1], bhl, acc[ct]);
            MFMA_(Wlo[ct],         bhh, acc[ct]);
        }
#pragma unroll
        for (int jt = 0; jt < 2; jt++) {
            acc[4 + jt] = __builtin_amdgcn_mfma_f32_16x16x32_f16(
                              Whi[8 + jt], bxh, biasreg[4 + jt], 0, 0, 0);
            acc[6 + jt] = __builtin_amdgcn_mfma_f32_16x16x32_f16(
                              Whi[10 + jt], bhh, biasreg[6 + jt], 0, 0, 0);
            MFMA_(Whi[10 + jt], bhl, acc[6 + jt]);
            MFMA_(Wlo[4 + jt],  bhh, acc[6 + jt]);
        }

        // Epilogue, f32x2-packed over row pairs (adjacent acc subregisters ->
        // v_pk_* ops, no marshaling). Same op order as the scalar version:
        // batched rcp (1 per 4 sigmoid denoms, 1 per 2 tanh denoms).
#pragma unroll
        for (int jt = 0; jt < 2; jt++) {
            half4 h4, l4;
            float hv[4];
#pragma unroll
            for (int pr = 0; pr < 2; pr++) {
                f32x2 R2, Z2, I2, H2;
                R2[0] = acc[0 + jt][2 * pr]; R2[1] = acc[0 + jt][2 * pr + 1];
                Z2[0] = acc[2 + jt][2 * pr]; Z2[1] = acc[2 + jt][2 * pr + 1];
                I2[0] = acc[4 + jt][2 * pr]; I2[1] = acc[4 + jt][2 * pr + 1];
                H2[0] = acc[6 + jt][2 * pr]; H2[1] = acc[6 + jt][2 * pr + 1];
                f32x2 av, bv;
                av[0] = __builtin_amdgcn_exp2f(R2[0]);
                av[1] = __builtin_amdgcn_exp2f(R2[1]);
                bv[0] = __builtin_amdgcn_exp2f(Z2[0]);
                bv[1] = __builtin_amdgcn_exp2f(Z2[1]);
                av = av + 1.0f;                       // pk_add
                bv = bv + 1.0f;
                f32x2 pv = av * bv;                   // pk_mul
                float q  = __builtin_amdgcn_rcpf(pv[0] * pv[1]);
                f32x2 qs; qs[0] = q * pv[1]; qs[1] = q * pv[0];   // = 1/p0, 1/p1
                f32x2 rv = qs * bv;                   // = 1/a
                f32x2 zv = qs * av;                   // = 1/b
                f32x2 na = __builtin_elementwise_fma(rv, H2, I2);
                f32x2 ea;
                ea[0] = __builtin_amdgcn_exp2f(na[0]);
                ea[1] = __builtin_amdgcn_exp2f(na[1]);
                f32x2 dv = ea + 1.0f;
                float qn = __builtin_amdgcn_rcpf(dv[0] * dv[1]);
                f32x2 qv; qv[0] = qn * dv[1]; qv[1] = qn * dv[0]; // = 1/d0, 1/d1
                f32x2 m2; m2[0] = -2.0f; m2[1] = -2.0f;
                f32x2 o1; o1[0] = 1.0f;  o1[1] = 1.0f;
                f32x2 nv = __builtin_elementwise_fma(m2, qv, o1);
                f32x2 hp = hprev[jt * 2 + pr];
                f32x2 hn = __builtin_elementwise_fma(zv, hp - nv, nv);
                hprev[jt * 2 + pr] = hn;
                _Float16 hh0 = (_Float16)hn[0], hh1 = (_Float16)hn[1];
                f32x2 hi32; hi32[0] = (float)hh0; hi32[1] = (float)hh1;
                f32x2 lo2 = hn - hi32;               // pk_sub
                h4[2 * pr]     = hh0; h4[2 * pr + 1] = hh1;
                l4[2 * pr]     = (_Float16)lo2[0];
                l4[2 * pr + 1] = (_Float16)lo2[1];
                hv[2 * pr]     = hn[0];
                hv[2 * pr + 1] = hn[1];
            }
            int wi = jt * 256 + wibase;
            *(half4*)(lds16 + ownhi + ((t & 7) << 9) + wi) = h4;
            *(half4*)(lds16 + ownlo + ((t & 1) << 9) + wi) = l4;
            if (w == LL - 1 && t == capT) {
                float4 o = make_float4(hv[0], hv[1], hv[2], hv[3]);
                *(float4*)(last + (size_t)(bg * 16 + bi16) * HH + jt * 16 + quad * 4) = o;
            }
        }
    };

    for (int t = 0; t < TT; t += 2) {
        // fwd sync: input panels for t, t+1 published by wave w-1
        if (w > 0) {
            while (__hip_atomic_load(&flagS[w - 1], __ATOMIC_ACQUIRE,
                                     __HIP_MEMORY_SCOPE_WORKGROUP) < t + 1)
                __builtin_amdgcn_s_sleep(1);
        }
        // bwd sync: writing t+1 reuses slot of t-7 — consumer must be done
        if (w < LL - 1) {
            while (__hip_atomic_load(&rflagS[w], __ATOMIC_ACQUIRE,
                                     __HIP_MEMORY_SCOPE_WORKGROUP) < t - 7)
                __builtin_amdgcn_s_sleep(1);
        }

        // wave 0: issue global x loads for t+2, t+3 early
        float4 xa0, xa1;
        bool dl0 = false, dl1 = false;
        if (xlane) {
            if (t + 2 < TT) {
                xa0 = *(const float4*)(x + (size_t)(t + 2) * BB * IN_DIM +
                                       (size_t)bg * 192 + lane * 4);
                dl0 = true;
            }
            if (t + 3 < TT) {
                xa1 = *(const float4*)(x + (size_t)(t + 3) * BB * IN_DIM +
                                       (size_t)bg * 192 + lane * 4);
                dl1 = true;
            }
        }

        substep(t);
        substep(t + 1);

        if (dl0) stage_x(xa0, t + 2);   // 4 x-slots: no overlap with t, t+1
        if (dl1) stage_x(xa1, t + 3);

        if (lane == 0) {
            // release: waits for this wave's DS ops (panel writes AND input
            // reads) to drain before publishing
            if (w < LL - 1)
                __hip_atomic_store(&flagS[w], t + 1, __ATOMIC_RELEASE,
                                   __HIP_MEMORY_SCOPE_WORKGROUP);
            if (w > 0)
                __hip_atomic_store(&rflagS[w - 1], t + 1, __ATOMIC_RELEASE,
                                   __HIP_MEMORY_SCOPE_WORKGROUP);
        }
    }
}

__global__ __launch_bounds__(256)
void fc_head(const float* __restrict__ last,
             const float* __restrict__ fcW,   // [C][H]
             const float* __restrict__ fcb,   // [C]
             float* __restrict__ out)         // [B][C]
{
    int b = blockIdx.x * blockDim.x + threadIdx.x;
    if (b >= BB) return;
    float lg[CC];
#pragma unroll
    for (int c = 0; c < CC; c++) lg[c] = fcb[c];
#pragma unroll
    for (int j = 0; j < HH; j++) {
        float h = last[(size_t)b * HH + j];
#pragma unroll
        for (int c = 0; c < CC; c++) lg[c] = fmaf(fcW[c * HH + j], h, lg[c]);
    }
    float m = lg[0];
#pragma unroll
    for (int c = 1; c < CC; c++) m = fmaxf(m, lg[c]);
    float s = 0.0f;
#pragma unroll
    for (int c = 0; c < CC; c++) s += __expf(lg[c] - m);
    float lse = m + logf(s);
#pragma unroll
    for (int c = 0; c < CC; c++) out[(size_t)b * CC + c] = lg[c] - lse;
}

extern "C" void kernel_launch(void* const* d_in, const int* in_sizes, int n_in,
                              void* d_out, int out_size, void* d_ws, size_t ws_size,
                              hipStream_t stream)
{
    const float* x    = (const float*)d_in[0];
    const float* Wih0 = (const float*)d_in[1];
    const float* Whh0 = (const float*)d_in[2];
    const float* bih0 = (const float*)d_in[3];
    const float* bhh0 = (const float*)d_in[4];
    const float* Wih  = (const float*)d_in[5];
    const float* Whh  = (const float*)d_in[6];
    const float* bih  = (const float*)d_in[7];
    const float* bhh  = (const float*)d_in[8];
    const float* fcW  = (const float*)d_in[9];
    const float* fcb  = (const float*)d_in[10];
    const int*   lens = (const int*)d_in[11];
    float* out = (float*)d_out;

    float* last = (float*)d_ws;   // [B][32] = 512 KB

    gru_fused_mfma<<<dim3(BB / 16), dim3(NTH), 0, stream>>>(
        x, Wih0, Whh0, bih0, bhh0, Wih, Whh, bih, bhh, lens, last);

    fc_head<<<dim3(BB / 256), dim3(256), 0, stream>>>(last, fcW, fcb, out);
}